// Round 5
// baseline (17402.647 us; speedup 1.0000x reference)
//
#include <hip/hip_runtime.h>

// ============================================================================
// 2-layer LSTM (B=256, T=1024, H=512, in=1) + linear head. fp32 in/out.
//
// R5: R4 dataflow pipeline (256 blocks x 256 thr, 4 batch chunks; L0 16
// slices/chunk, L1 32 slices/chunk, per-slice flags, RING=16) with the h
// transport moved from DRAM to the cache hierarchy.
//  R4 counter forensics: WRITE_SIZE ~= h-store volume, FETCH_SIZE ~= unique
//  h-read volume => sc1 write-through stores DO NOT allocate in LLC; the
//  recurrent exchange was bouncing off HBM (~900cy/handoff, twice a step).
//  R5 producer release (manual agent-release, gfx94x style):
//    plain write-back stores -> s_waitcnt vmcnt(0) -> buffer_wbl2 sc1 ->
//    s_waitcnt vmcnt(0) -> sc1 flag store.
//  L2 write-back allocates in the memory-side Infinity Cache, so consumers'
//  plain cached loads (+ per-WG buffer_inv once per RING epoch, which only
//  kills L1/L2 copies, never the LLC) hit LLC/L2, not HBM.
//  Dirty-line hygiene: only h lines are ever dirty (part8 uses RMW atomics,
//  everything else is read-only), and they are wbl2-flushed before the flag
//  every step => epoch buffer_inv can never drop unwritten data.
//  Polls: wv0-only + __syncthreads release (4x less flag-line pressure).
// h = fp16 hi + (lo*1024) split; MFMA f32_16x16x32_f16; fp32 cell state in
// regs. Math identical to R1-R4 (absmax 6.1e-5 verified).
// ============================================================================

typedef _Float16 f16;
typedef _Float16 f16x8 __attribute__((ext_vector_type(8)));
typedef float f32x4 __attribute__((ext_vector_type(4)));
typedef unsigned long long u64;

#define NB 256
#define NT_ 1024
#define NH 512
#define RING 16
#define SLOT (NB * NH)

__device__ __forceinline__ float sigm(float x)  { return 1.0f / (1.0f + __expf(-x)); }
__device__ __forceinline__ float tanhx(float x) { return 2.0f / (1.0f + __expf(-2.0f * x)) - 1.0f; }

__device__ __forceinline__ unsigned ldf(const unsigned* p) {
  return __hip_atomic_load(p, __ATOMIC_RELAXED, __HIP_MEMORY_SCOPE_AGENT);
}
// wv0-only: poll nf flags until all >= thr (lane-parallel, one line), then
// caller releases the WG via __syncthreads(). asm clobber pins load order.
__device__ __forceinline__ void pollf(const unsigned* base, int nf, unsigned thr, int ln) {
  const unsigned* a = base + (ln & (nf - 1));
  for (;;) {
    unsigned v = ldf(a);
    if (!~__ballot(v >= thr)) break;
    __builtin_amdgcn_s_sleep(1);
  }
  asm volatile("" ::: "memory");
}
// producer release: drain stores to L2, write L2 back to LLC, then publish.
__device__ __forceinline__ void release_wbl2() {
  asm volatile("s_waitcnt vmcnt(0)\n\t"
               "buffer_wbl2 sc1\n\t"
               "s_waitcnt vmcnt(0)" ::: "memory");
}

// ---------------------------------------------------------------------------
__global__ void prep_xT(const float* __restrict__ inp, float* __restrict__ xT) {
  int g = blockIdx.x * 256 + threadIdx.x;
  int t = g >> 8, b = g & 255;
  xT[t * NB + b] = inp[b * NT_ + t];
}

// ---------------------------------------------------------------------------
// fp32 -> fp16 weights in MFMA B-fragment order (verified R3/R4).
__global__ void prep_w(const float* __restrict__ Wh0,
                       const float* __restrict__ Wx1,
                       const float* __restrict__ Wh1,
                       f16* __restrict__ dst) {
  int g = blockIdx.x * 256 + threadIdx.x;   // 3 * 2^20 threads
  int mat = g >> 20;
  int r = g & 0xFFFFF;
  int j = r & 7, ln = (r >> 3) & 63, kt = (r >> 9) & 15;
  int cl = ln & 15, qd = ln >> 4;
  int k = kt * 32 + qd * 8 + j;
  size_t di; int gcol; const float* W;
  if (mat == 0) {
    int gt = (r >> 13) & 3, nh = (r >> 15) & 1, sl = (r >> 16) & 15;
    W = Wh0;
    gcol = gt * 512 + sl * 32 + nh * 16 + cl;
    di = (size_t)sl * 65536 + (((size_t)(nh * 4 + gt) * 16 + kt) * 64 + ln) * 8 + j;
  } else {
    int jt = (r >> 13) & 1, nh = (r >> 14) & 1, sl = (r >> 15) & 31;
    W = (mat == 1) ? Wx1 : Wh1;
    int gate = jt * 2 + (cl >> 3);
    gcol = gate * 512 + sl * 16 + nh * 8 + (cl & 7);
    di = (size_t)mat * 1048576 + (size_t)sl * 32768 +
         (((size_t)(nh * 2 + jt) * 16 + kt) * 64 + ln) * 8 + j;
  }
  dst[di] = (f16)W[(size_t)k * 2048 + gcol];
}

// ---------------------------------------------------------------------------
__global__ void reduce_out(const float* __restrict__ part8,
                           const float* __restrict__ bfp,
                           float* __restrict__ out) {
  int g = blockIdx.x * 256 + threadIdx.x;   // 262144 = b*1024+t
  float v = bfp[0];
#pragma unroll
  for (int j = 0; j < 8; ++j) v += part8[(size_t)j * (NB * NT_) + g];
  out[g] = v;
}

// ---------------------------------------------------------------------------
__global__ __launch_bounds__(256) void lstm_main(
    const float* __restrict__ xT,       // [T][B]
    const f16*  __restrict__ wsl,       // tiled fp16 weights (6 MB)
    const float* __restrict__ wx0,      // [2048]
    const float* __restrict__ bias0,    // [2048]
    const float* __restrict__ bias1,    // [2048]
    const float* __restrict__ wf,       // [512]
    unsigned short* p_hi, unsigned short* p_lo,   // [RING][B][H]
    unsigned short* q_hi, unsigned short* q_lo,   // [RING][B][H]
    unsigned int* pf,                   // [4][32] L0 slice flags (16 used)
    unsigned int* qf,                   // [4][32] L1 slice flags
    float* part8)                       // [8][B][T]
{
  extern __shared__ char smem[];
  const int tid = threadIdx.x;
  const int wv = tid >> 6, ln = tid & 63;
  const int qd = ln >> 4, cl = ln & 15;
  const int bx = blockIdx.x;
  const int r8 = bx & 7, idx = bx >> 3;
  const bool isL0 = !(r8 & 1);
  const int c = r8 >> 1;
  const int sl = idx;
  if (isL0 && idx >= 16) return;        // 64 spare WGs exit
  const float LO = 1.0f / 1024.0f;
  const int rb = c * 64 + wv * 16;      // this wave's batch-row base

  // ---- stage weight slice(s) into LDS (once) ----
  if (isL0) {
    const int4* s0 = (const int4*)wsl + (size_t)sl * 8192;           // 128 KB
    int4* d = (int4*)smem;
    for (int i = tid; i < 8192; i += 256) d[i] = s0[i];
  } else {
    const int4* s1 = (const int4*)wsl + 131072 + (size_t)sl * 4096;  // Wx1 64 KB
    const int4* s2 = (const int4*)wsl + 262144 + (size_t)sl * 4096;  // Wh1 64 KB
    int4* d = (int4*)smem;
    for (int i = tid; i < 4096; i += 256) { d[i] = s1[i]; d[4096 + i] = s2[i]; }
  }
  __syncthreads();

  // ---- loop-invariant constants ----
  float wx0v[2][4], b0c[2][4];
  float b1c0[2], b1c1[2], wfv[2];
  if (isL0) {
#pragma unroll
    for (int nh = 0; nh < 2; ++nh)
#pragma unroll
      for (int g = 0; g < 4; ++g) {
        int gc = g * 512 + sl * 32 + nh * 16 + cl;
        wx0v[nh][g] = wx0[gc];
        b0c[nh][g] = bias0[gc];
      }
  } else {
    int u = cl & 7, g01 = cl >> 3;
#pragma unroll
    for (int nh = 0; nh < 2; ++nh) {
      int base = sl * 16 + nh * 8 + u;
      b1c0[nh] = bias1[g01 * 512 + base];
      b1c1[nh] = bias1[(2 + g01) * 512 + base];
      wfv[nh] = wf[base];
    }
  }
  unsigned* pfc = pf + c * 32;
  unsigned* qfc = qf + c * 32;
  float cst[2][4] = {{0.f,0.f,0.f,0.f},{0.f,0.f,0.f,0.f}};

  for (int s = 0; s < NT_; ++s) {
    // ---- ring-epoch L1/L2 invalidate (per-WG; LLC copies survive) ----
    if ((s & (RING - 1)) == 0 && s) {
      __syncthreads();
      if (wv == 0)
        asm volatile("buffer_inv sc1\n\ts_waitcnt vmcnt(0)" ::: "memory");
      __syncthreads();
    }
    const int slot_r = (s + RING - 1) & (RING - 1);   // h_{s-1}
    const int slot_w = s & (RING - 1);                // h_s

    if (isL0) {
      // ======== layer 0: p_s = LSTM(x_s, p_{s-1}) ========
      if (s) {
        if (wv == 0) pollf(pfc, 16, (unsigned)s, ln);  // peers done s-1
        __syncthreads();
      }
      float xv[4];
#pragma unroll
      for (int e = 0; e < 4; ++e) xv[e] = xT[s * NB + rb + qd * 4 + e];
      const f16* ah = (const f16*)p_hi + (size_t)slot_r * SLOT + (size_t)(rb + cl) * NH + qd * 8;
      const f16* al = (const f16*)p_lo + (size_t)slot_r * SLOT + (size_t)(rb + cl) * NH + qd * 8;
      const f16x8* wl = (const f16x8*)smem;
      f32x4 acc[8]  = {};
      f32x4 accL[8] = {};
#pragma unroll
      for (int kt = 0; kt < 16; ++kt) {
        f16x8 a0 = *(const f16x8*)(ah + kt * 32);
        f16x8 a1 = *(const f16x8*)(al + kt * 32);
#pragma unroll
        for (int t8 = 0; t8 < 8; ++t8) {   // t8 = nh*4 + gate
          f16x8 bw = wl[(t8 * 16 + kt) * 64 + ln];
          acc[t8]  = __builtin_amdgcn_mfma_f32_16x16x32_f16(a0, bw, acc[t8], 0, 0, 0);
          accL[t8] = __builtin_amdgcn_mfma_f32_16x16x32_f16(a1, bw, accL[t8], 0, 0, 0);
        }
      }
      f16* sh  = (f16*)(smem + 131072);      // 64 x 32 hi (4 KB)
      f16* slo = sh + 2048;                  // 64 x 32 lo (4 KB)
#pragma unroll
      for (int nh = 0; nh < 2; ++nh)
#pragma unroll
        for (int e = 0; e < 4; ++e) {
          int r = wv * 16 + qd * 4 + e;
          float gi = acc[nh*4+0][e] + accL[nh*4+0][e] * LO + xv[e] * wx0v[nh][0] + b0c[nh][0];
          float gf = acc[nh*4+1][e] + accL[nh*4+1][e] * LO + xv[e] * wx0v[nh][1] + b0c[nh][1];
          float gg = acc[nh*4+2][e] + accL[nh*4+2][e] * LO + xv[e] * wx0v[nh][2] + b0c[nh][2];
          float go = acc[nh*4+3][e] + accL[nh*4+3][e] * LO + xv[e] * wx0v[nh][3] + b0c[nh][3];
          float ii = sigm(gi), ff = sigm(gf), tg = tanhx(gg), oo = sigm(go);
          cst[nh][e] = ff * cst[nh][e] + ii * tg;
          float h = oo * tanhx(cst[nh][e]);
          f16 hh = (f16)h;
          sh[r * 32 + nh * 16 + cl]  = hh;
          slo[r * 32 + nh * 16 + cl] = (f16)((h - (float)hh) * 1024.0f);
        }
      __syncthreads();
      // ring-overwrite guard: L1 must have finished step s-16
      if (s >= RING) {
        if (wv == 0) pollf(qfc, 32, (unsigned)(s - RING + 1), ln);
        __syncthreads();
      }
      // coop PLAIN write-back store: 64 rows x 32 units x {hi,lo}, 8B pieces
      {
        unsigned short* bh = p_hi + (size_t)slot_w * SLOT;
        unsigned short* bl = p_lo + (size_t)slot_w * SLOT;
        for (int i = tid; i < 1024; i += 256) {
          int strm = i >> 9, id2 = i & 511, r = id2 >> 3, j = id2 & 7;
          const f16* src = (strm ? slo : sh) + r * 32 + j * 4;
          unsigned short* dst = (strm ? bl : bh) + (size_t)(c * 64 + r) * NH + sl * 32 + j * 4;
          *(u64*)dst = *(const u64*)src;
        }
      }
      __syncthreads();   // every wave's stores are issued (and in L2)
      if (wv == 0) {
        release_wbl2();  // flush dirty h lines to LLC
        if (ln == 0)
          __hip_atomic_store(pfc + sl, (unsigned)(s + 1),
                             __ATOMIC_RELAXED, __HIP_MEMORY_SCOPE_AGENT);
      }
    } else {
      // ======== layer 1: q_s = LSTM(p_s, q_{s-1}) ========
      // phase 1: q_{s-1} @ Wh1
      if (s) {
        if (wv == 0) pollf(qfc, 32, (unsigned)s, ln);
        __syncthreads();
      }
      const f16* aqh = (const f16*)q_hi + (size_t)slot_r * SLOT + (size_t)(rb + cl) * NH + qd * 8;
      const f16* aql = (const f16*)q_lo + (size_t)slot_r * SLOT + (size_t)(rb + cl) * NH + qd * 8;
      const f16x8* wx_ = (const f16x8*)smem;
      const f16x8* wh_ = (const f16x8*)(smem + 65536);
      f32x4 acc[4]  = {};
      f32x4 accL[4] = {};
#pragma unroll
      for (int kt = 0; kt < 16; ++kt) {
        f16x8 a0 = *(const f16x8*)(aqh + kt * 32);
        f16x8 a1 = *(const f16x8*)(aql + kt * 32);
#pragma unroll
        for (int t4 = 0; t4 < 4; ++t4) {   // t4 = nh*2 + jt
          f16x8 bw = wh_[(t4 * 16 + kt) * 64 + ln];
          acc[t4]  = __builtin_amdgcn_mfma_f32_16x16x32_f16(a0, bw, acc[t4], 0, 0, 0);
          accL[t4] = __builtin_amdgcn_mfma_f32_16x16x32_f16(a1, bw, accL[t4], 0, 0, 0);
        }
      }
      // phase 2: p_s @ Wx1
      if (wv == 0) pollf(pfc, 16, (unsigned)(s + 1), ln);
      __syncthreads();
      const f16* aph = (const f16*)p_hi + (size_t)slot_w * SLOT + (size_t)(rb + cl) * NH + qd * 8;
      const f16* apl = (const f16*)p_lo + (size_t)slot_w * SLOT + (size_t)(rb + cl) * NH + qd * 8;
#pragma unroll
      for (int kt = 0; kt < 16; ++kt) {
        f16x8 a0 = *(const f16x8*)(aph + kt * 32);
        f16x8 a1 = *(const f16x8*)(apl + kt * 32);
#pragma unroll
        for (int t4 = 0; t4 < 4; ++t4) {
          f16x8 bw = wx_[(t4 * 16 + kt) * 64 + ln];
          acc[t4]  = __builtin_amdgcn_mfma_f32_16x16x32_f16(a0, bw, acc[t4], 0, 0, 0);
          accL[t4] = __builtin_amdgcn_mfma_f32_16x16x32_f16(a1, bw, accL[t4], 0, 0, 0);
        }
      }
      f16* sh  = (f16*)(smem + 131072);    // 64 x 16 hi (2 KB)
      f16* slo = sh + 1024;                // 64 x 16 lo (2 KB)
      const bool hiH = (cl < 8);
#pragma unroll
      for (int e = 0; e < 4; ++e) {
        int r = wv * 16 + qd * 4 + e;
        int b = c * 64 + r;
        float po = 0.0f;
#pragma unroll
        for (int nh = 0; nh < 2; ++nh) {
          float v0 = acc[nh*2+0][e] + accL[nh*2+0][e] * LO + b1c0[nh];   // i / f
          float v1 = acc[nh*2+1][e] + accL[nh*2+1][e] * LO + b1c1[nh];   // g / o
          float w0 = __shfl_xor(v0, 8, 16);
          float w1 = __shfl_xor(v1, 8, 16);
          float gi = hiH ? v0 : w0;
          float gf = hiH ? w0 : v0;
          float gg = hiH ? v1 : w1;
          float go = hiH ? w1 : v1;
          float ii = sigm(gi), ff = sigm(gf), tg = tanhx(gg), oo = sigm(go);
          cst[nh][e] = ff * cst[nh][e] + ii * tg;
          float h = oo * tanhx(cst[nh][e]);
          int su = r * 16 + nh * 8 + (cl & 7);
          if (hiH) {
            sh[su] = (f16)h;
          } else {
            f16 hh = (f16)h;
            slo[su] = (f16)((h - (float)hh) * 1024.0f);
          }
          po += hiH ? wfv[nh] * h : 0.0f;
        }
#pragma unroll
        for (int m = 1; m < 16; m <<= 1) po += __shfl_xor(po, m, 16);
        if (cl == 0)
          atomicAdd(part8 + (size_t)(sl & 7) * (NB * NT_) + (size_t)b * NT_ + s, po);
      }
      __syncthreads();
      // coop PLAIN write-back store: 64 rows x 16 units x {hi,lo}, 8B pieces
      {
        unsigned short* bh = q_hi + (size_t)slot_w * SLOT;
        unsigned short* bl = q_lo + (size_t)slot_w * SLOT;
        for (int i = tid; i < 512; i += 256) {
          int strm = i >> 8, id2 = i & 255, r = id2 >> 2, j = id2 & 3;
          const f16* src = (strm ? slo : sh) + r * 16 + j * 4;
          unsigned short* dst = (strm ? bl : bh) + (size_t)(c * 64 + r) * NH + sl * 16 + j * 4;
          *(u64*)dst = *(const u64*)src;
        }
      }
      __syncthreads();
      if (wv == 0) {
        release_wbl2();
        if (ln == 0)
          __hip_atomic_store(qfc + sl, (unsigned)(s + 1),
                             __ATOMIC_RELAXED, __HIP_MEMORY_SCOPE_AGENT);
      }
    }
  }
}

// ---------------------------------------------------------------------------
extern "C" void kernel_launch(void* const* d_in, const int* in_sizes, int n_in,
                              void* d_out, int out_size, void* d_ws, size_t ws_size,
                              hipStream_t stream) {
  (void)in_sizes; (void)n_in; (void)out_size; (void)ws_size;
  const float* inp = (const float*)d_in[0];
  const float* Wx0 = (const float*)d_in[1];
  const float* Wh0 = (const float*)d_in[2];
  const float* b0  = (const float*)d_in[3];
  const float* Wx1 = (const float*)d_in[4];
  const float* Wh1 = (const float*)d_in[5];
  const float* b1  = (const float*)d_in[6];
  const float* Wf  = (const float*)d_in[7];
  const float* bf  = (const float*)d_in[8];

  const size_t MB = 1u << 20;
  const size_t OFF_W    = 0;                 // 6 MiB tiled fp16 weights
  const size_t OFF_XT   = 6 * MB;            // 1 MiB
  const size_t OFF_PHI  = 7 * MB;            // 4 MiB (RING x 256 KB)
  const size_t OFF_PLO  = 11 * MB;
  const size_t OFF_QHI  = 15 * MB;
  const size_t OFF_QLO  = 19 * MB;
  const size_t OFF_PART = 23 * MB;           // 8 MiB
  const size_t OFF_CTR  = 31 * MB;           // flags: pf 512 B + qf 512 B

  char* ws = (char*)d_ws;
  f16* wsl = (f16*)(ws + OFF_W);
  float* xT = (float*)(ws + OFF_XT);
  unsigned short* phi = (unsigned short*)(ws + OFF_PHI);
  unsigned short* plo = (unsigned short*)(ws + OFF_PLO);
  unsigned short* qhi = (unsigned short*)(ws + OFF_QHI);
  unsigned short* qlo = (unsigned short*)(ws + OFF_QLO);
  float* part8 = (float*)(ws + OFF_PART);
  unsigned int* pfl = (unsigned int*)(ws + OFF_CTR);
  unsigned int* qfl = pfl + 128;
  float* out = (float*)d_out;

  hipFuncSetAttribute((const void*)lstm_main,
                      hipFuncAttributeMaxDynamicSharedMemorySize, 139264);

  // zero rings + partials + flags (contiguous)
  hipMemsetAsync(ws + OFF_PHI, 0, (OFF_CTR + 1024) - OFF_PHI, stream);

  prep_xT<<<1024, 256, 0, stream>>>(inp, xT);
  prep_w<<<12288, 256, 0, stream>>>(Wh0, Wx1, Wh1, wsl);

  lstm_main<<<256, 256, 139264, stream>>>(xT, wsl, Wx0, b0, b1, Wf,
                                          phi, plo, qhi, qlo, pfl, qfl, part8);

  reduce_out<<<1024, 256, 0, stream>>>(part8, bf, out);
}

// Round 7
// 13373.094 us; speedup vs baseline: 1.3013x; 1.3013x over previous
//
#include <hip/hip_runtime.h>

// ============================================================================
// 2-layer LSTM (B=256, T=1024, H=512, in=1) + linear head. fp32 in/out.
//
// R7 = R6 with the fast-flag deadlock fixed.
//  R6 hang forensics: fast flags are plain (write-back) stores -> dirty L2
//  lines. Unsynchronized per-WG epoch buffer_inv can discard them; LLC copy
//  is stale; a blocked producer never re-stores -> consumer spins forever.
//  R7: pollT = bounded fast phase (8 sc0 L2-latency polls) + safe LLC poll
//  every outer iteration. Progress guaranteed by the agent-scope safe flag
//  alone; fast tier is purely a latency accelerator. Fast values are
//  monotonic so a stale read is only ever LOW (= wait longer), never wrong.
//  XCD placement exchange is bounded: timeout -> fastg=false (R4 behavior).
// Base protocol (R4, passed, absmax 6.1e-5): 256x256 grid, 4 batch chunks;
// L0 16 slices/chunk (128KB Wh0 LDS), L1 32 slices/chunk (Wx1+Wh1 128KB);
// RING=16 h slots; sc1 WT h-stores; plain cached h-loads; per-WG epoch
// buffer_inv; per-slice flags; L1 q-phase before p-poll; part8 + reduce.
// h = fp16 hi + (lo*1024); MFMA f32_16x16x32_f16; fp32 cell state in regs.
// ============================================================================

typedef _Float16 f16;
typedef _Float16 f16x8 __attribute__((ext_vector_type(8)));
typedef float f32x4 __attribute__((ext_vector_type(4)));
typedef unsigned long long u64;

#define NB 256
#define NT_ 1024
#define NH 512
#define RING 16
#define SLOT (NB * NH)
// s_getreg imm: ID=20 (HW_REG_XCC_ID), offset 0, size 32
#define XCC_GETREG_IMM (20 | (31 << 11))

__device__ __forceinline__ float sigm(float x)  { return 1.0f / (1.0f + __expf(-x)); }
__device__ __forceinline__ float tanhx(float x) { return 2.0f / (1.0f + __expf(-2.0f * x)) - 1.0f; }

__device__ __forceinline__ void st8(unsigned short* p, u64 v) {
  __hip_atomic_store((u64*)p, v, __ATOMIC_RELAXED, __HIP_MEMORY_SCOPE_AGENT);
}
__device__ __forceinline__ unsigned ldS(const unsigned* p) {
  return __hip_atomic_load(p, __ATOMIC_RELAXED, __HIP_MEMORY_SCOPE_AGENT);
}
// safe poll: LLC-scope flag read, lane-parallel over one line + ballot.
__device__ __forceinline__ void pollS(const unsigned* base, int nf, unsigned thr, int ln) {
  const unsigned* a = base + (ln & (nf - 1));
  for (;;) {
    unsigned v = ldS(a);
    if (!~__ballot(v >= thr)) break;
    __builtin_amdgcn_s_sleep(1);
  }
  asm volatile("" ::: "memory");
}
// two-tier poll: fast sc0 (L1-bypass, L2-hit) polls of the plain-store flag,
// with a guaranteed-progress safe LLC poll every outer iteration. Fast flag
// values are monotonic: stale reads are only ever low, never wrong.
__device__ __forceinline__ void pollT(const unsigned* fastp, const unsigned* safep,
                                      int nf, unsigned thr, int ln) {
  const unsigned* af = fastp + (ln & (nf - 1));
  const unsigned* as = safep + (ln & (nf - 1));
  for (;;) {
#pragma unroll 1
    for (int k = 0; k < 8; ++k) {
      unsigned v;
      asm volatile("global_load_dword %0, %1, off sc0\n\t"
                   "s_waitcnt vmcnt(0)"
                   : "=v"(v) : "v"(af) : "memory");
      if (!~__ballot(v >= thr)) { asm volatile("" ::: "memory"); return; }
    }
    unsigned v = ldS(as);                 // progress guarantee (LLC flag)
    if (!~__ballot(v >= thr)) break;
    __builtin_amdgcn_s_sleep(1);
  }
  asm volatile("" ::: "memory");
}

// ---------------------------------------------------------------------------
__global__ void prep_xT(const float* __restrict__ inp, float* __restrict__ xT) {
  int g = blockIdx.x * 256 + threadIdx.x;
  int t = g >> 8, b = g & 255;
  xT[t * NB + b] = inp[b * NT_ + t];
}

// ---------------------------------------------------------------------------
// fp32 -> fp16 weights in MFMA B-fragment order (verified R3/R4).
__global__ void prep_w(const float* __restrict__ Wh0,
                       const float* __restrict__ Wx1,
                       const float* __restrict__ Wh1,
                       f16* __restrict__ dst) {
  int g = blockIdx.x * 256 + threadIdx.x;   // 3 * 2^20 threads
  int mat = g >> 20;
  int r = g & 0xFFFFF;
  int j = r & 7, ln = (r >> 3) & 63, kt = (r >> 9) & 15;
  int cl = ln & 15, qd = ln >> 4;
  int k = kt * 32 + qd * 8 + j;
  size_t di; int gcol; const float* W;
  if (mat == 0) {
    int gt = (r >> 13) & 3, nh = (r >> 15) & 1, sl = (r >> 16) & 15;
    W = Wh0;
    gcol = gt * 512 + sl * 32 + nh * 16 + cl;
    di = (size_t)sl * 65536 + (((size_t)(nh * 4 + gt) * 16 + kt) * 64 + ln) * 8 + j;
  } else {
    int jt = (r >> 13) & 1, nh = (r >> 14) & 1, sl = (r >> 15) & 31;
    W = (mat == 1) ? Wx1 : Wh1;
    int gate = jt * 2 + (cl >> 3);
    gcol = gate * 512 + sl * 16 + nh * 8 + (cl & 7);
    di = (size_t)mat * 1048576 + (size_t)sl * 32768 +
         (((size_t)(nh * 2 + jt) * 16 + kt) * 64 + ln) * 8 + j;
  }
  dst[di] = (f16)W[(size_t)k * 2048 + gcol];
}

// ---------------------------------------------------------------------------
__global__ void reduce_out(const float* __restrict__ part8,
                           const float* __restrict__ bfp,
                           float* __restrict__ out) {
  int g = blockIdx.x * 256 + threadIdx.x;   // 262144 = b*1024+t
  float v = bfp[0];
#pragma unroll
  for (int j = 0; j < 8; ++j) v += part8[(size_t)j * (NB * NT_) + g];
  out[g] = v;
}

// ---------------------------------------------------------------------------
// sync layout (uints): pfS[128] qfS[128] pfF[128] qfF[128] xcdtab[256]
__global__ __launch_bounds__(256) void lstm_main(
    const float* __restrict__ xT,       // [T][B]
    const f16*  __restrict__ wsl,       // tiled fp16 weights (6 MB)
    const float* __restrict__ wx0,      // [2048]
    const float* __restrict__ bias0,    // [2048]
    const float* __restrict__ bias1,    // [2048]
    const float* __restrict__ wf,       // [512]
    unsigned short* p_hi, unsigned short* p_lo,   // [RING][B][H]
    unsigned short* q_hi, unsigned short* q_lo,   // [RING][B][H]
    unsigned int* sync,
    float* part8)                       // [8][B][T]
{
  extern __shared__ char smem[];
  const int tid = threadIdx.x;
  const int wv = tid >> 6, ln = tid & 63;
  const int qd = ln >> 4, cl = ln & 15;
  const int bx = blockIdx.x;
  const int r8 = bx & 7, idx = bx >> 3;
  const bool isL0 = !(r8 & 1);
  const int c = r8 >> 1;
  const int sl = idx;
  if (isL0 && idx >= 16) return;        // 64 spare WGs exit
  const float LO = 1.0f / 1024.0f;
  const int rb = c * 64 + wv * 16;      // this wave's batch-row base

  unsigned* pfS = sync;
  unsigned* qfS = sync + 128;
  unsigned* pfF = sync + 256;
  unsigned* qfF = sync + 384;
  unsigned* xcdtab = sync + 512;

  // ---- stage weight slice(s) into LDS (once) ----
  if (isL0) {
    const int4* s0 = (const int4*)wsl + (size_t)sl * 8192;           // 128 KB
    int4* d = (int4*)smem;
    for (int i = tid; i < 8192; i += 256) d[i] = s0[i];
  } else {
    const int4* s1 = (const int4*)wsl + 131072 + (size_t)sl * 4096;  // Wx1 64 KB
    const int4* s2 = (const int4*)wsl + 262144 + (size_t)sl * 4096;  // Wh1 64 KB
    int4* d = (int4*)smem;
    for (int i = tid; i < 4096; i += 256) { d[i] = s1[i]; d[4096 + i] = s2[i]; }
  }

  // ---- XCD placement exchange (bounded; timeout -> safe-poll mode) ----
  const unsigned xcc1 = (unsigned)(__builtin_amdgcn_s_getreg(XCC_GETREG_IMM) & 15) + 1u;
  if (tid == 0)
    __hip_atomic_store(xcdtab + bx, xcc1, __ATOMIC_RELAXED, __HIP_MEMORY_SCOPE_AGENT);
  bool fastg;
  {
    const int n = isL0 ? 16 : 32;       // my group: blocks {i*8 + r8, i < n}
    unsigned v = xcc1;
    if (ln < n) {
      const unsigned* a = xcdtab + (ln * 8 + r8);
      v = 0;
#pragma unroll 1
      for (int it = 0; it < (1 << 20) && v == 0; ++it) v = ldS(a);
    }
    fastg = !~__ballot(v == xcc1);      // all members verified same XCD
  }
  __syncthreads();

  // ---- loop-invariant constants ----
  float wx0v[2][4], b0c[2][4];
  float b1c0[2], b1c1[2], wfv[2];
  if (isL0) {
#pragma unroll
    for (int nh = 0; nh < 2; ++nh)
#pragma unroll
      for (int g = 0; g < 4; ++g) {
        int gc = g * 512 + sl * 32 + nh * 16 + cl;
        wx0v[nh][g] = wx0[gc];
        b0c[nh][g] = bias0[gc];
      }
  } else {
    int u = cl & 7, g01 = cl >> 3;
#pragma unroll
    for (int nh = 0; nh < 2; ++nh) {
      int base = sl * 16 + nh * 8 + u;
      b1c0[nh] = bias1[g01 * 512 + base];
      b1c1[nh] = bias1[(2 + g01) * 512 + base];
      wfv[nh] = wf[base];
    }
  }
  unsigned* pfSc = pfS + c * 32;
  unsigned* qfSc = qfS + c * 32;
  unsigned* pfFc = pfF + c * 32;
  unsigned* qfFc = qfF + c * 32;
  float cst[2][4] = {{0.f,0.f,0.f,0.f},{0.f,0.f,0.f,0.f}};

  for (int s = 0; s < NT_; ++s) {
    // ---- ring-epoch L1/L2 invalidate ----
    if ((s & (RING - 1)) == 0 && s) {
      __syncthreads();
      if (wv == 0)
        asm volatile("buffer_inv sc1\n\ts_waitcnt vmcnt(0)" ::: "memory");
      __syncthreads();
    }
    const int slot_r = (s + RING - 1) & (RING - 1);   // h_{s-1}
    const int slot_w = s & (RING - 1);                // h_s

    if (isL0) {
      // ======== layer 0: p_s = LSTM(x_s, p_{s-1}) ========
      if (s) {
        if (fastg) pollT(pfFc, pfSc, 16, (unsigned)s, ln);
        else       pollS(pfSc, 16, (unsigned)s, ln);
      }
      float xv[4];
#pragma unroll
      for (int e = 0; e < 4; ++e) xv[e] = xT[s * NB + rb + qd * 4 + e];
      const f16* ah = (const f16*)p_hi + (size_t)slot_r * SLOT + (size_t)(rb + cl) * NH + qd * 8;
      const f16* al = (const f16*)p_lo + (size_t)slot_r * SLOT + (size_t)(rb + cl) * NH + qd * 8;
      const f16x8* wl = (const f16x8*)smem;
      f32x4 acc[8]  = {};
      f32x4 accL[8] = {};
#pragma unroll
      for (int kt = 0; kt < 16; ++kt) {
        f16x8 a0 = *(const f16x8*)(ah + kt * 32);
        f16x8 a1 = *(const f16x8*)(al + kt * 32);
#pragma unroll
        for (int t8 = 0; t8 < 8; ++t8) {   // t8 = nh*4 + gate
          f16x8 bw = wl[(t8 * 16 + kt) * 64 + ln];
          acc[t8]  = __builtin_amdgcn_mfma_f32_16x16x32_f16(a0, bw, acc[t8], 0, 0, 0);
          accL[t8] = __builtin_amdgcn_mfma_f32_16x16x32_f16(a1, bw, accL[t8], 0, 0, 0);
        }
      }
      f16* sh  = (f16*)(smem + 131072);      // 64 x 32 hi (4 KB)
      f16* slo = sh + 2048;                  // 64 x 32 lo (4 KB)
#pragma unroll
      for (int nh = 0; nh < 2; ++nh)
#pragma unroll
        for (int e = 0; e < 4; ++e) {
          int r = wv * 16 + qd * 4 + e;
          float gi = acc[nh*4+0][e] + accL[nh*4+0][e] * LO + xv[e] * wx0v[nh][0] + b0c[nh][0];
          float gf = acc[nh*4+1][e] + accL[nh*4+1][e] * LO + xv[e] * wx0v[nh][1] + b0c[nh][1];
          float gg = acc[nh*4+2][e] + accL[nh*4+2][e] * LO + xv[e] * wx0v[nh][2] + b0c[nh][2];
          float go = acc[nh*4+3][e] + accL[nh*4+3][e] * LO + xv[e] * wx0v[nh][3] + b0c[nh][3];
          float ii = sigm(gi), ff = sigm(gf), tg = tanhx(gg), oo = sigm(go);
          cst[nh][e] = ff * cst[nh][e] + ii * tg;
          float h = oo * tanhx(cst[nh][e]);
          f16 hh = (f16)h;
          sh[r * 32 + nh * 16 + cl]  = hh;
          slo[r * 32 + nh * 16 + cl] = (f16)((h - (float)hh) * 1024.0f);
        }
      __syncthreads();
      // ring-overwrite guard: L1 (other XCD) must have finished step s-16
      if (s >= RING) pollS(qfSc, 32, (unsigned)(s - RING + 1), ln);
      // coop WT store: 64 rows x 32 units x {hi,lo}, 8B pieces
      {
        unsigned short* bh = p_hi + (size_t)slot_w * SLOT;
        unsigned short* bl = p_lo + (size_t)slot_w * SLOT;
        for (int i = tid; i < 1024; i += 256) {
          int strm = i >> 9, id2 = i & 511, r = id2 >> 3, j = id2 & 7;
          const f16* src = (strm ? slo : sh) + r * 32 + j * 4;
          unsigned short* dst = (strm ? bl : bh) + (size_t)(c * 64 + r) * NH + sl * 32 + j * 4;
          st8(dst, *(const u64*)src);
        }
      }
      __syncthreads();   // per-wave vmcnt(0) before barrier: stores drained
      if (tid == 0) {
        *(volatile unsigned*)(pfFc + sl) = (unsigned)(s + 1);   // fast L2 flag
        __hip_atomic_store(pfSc + sl, (unsigned)(s + 1),
                           __ATOMIC_RELAXED, __HIP_MEMORY_SCOPE_AGENT);
      }
    } else {
      // ======== layer 1: q_s = LSTM(p_s, q_{s-1}) ========
      // phase 1: q_{s-1} @ Wh1 (intra-XCD handshake)
      if (s) {
        if (fastg) pollT(qfFc, qfSc, 32, (unsigned)s, ln);
        else       pollS(qfSc, 32, (unsigned)s, ln);
      }
      const f16* aqh = (const f16*)q_hi + (size_t)slot_r * SLOT + (size_t)(rb + cl) * NH + qd * 8;
      const f16* aql = (const f16*)q_lo + (size_t)slot_r * SLOT + (size_t)(rb + cl) * NH + qd * 8;
      const f16x8* wx_ = (const f16x8*)smem;
      const f16x8* wh_ = (const f16x8*)(smem + 65536);
      f32x4 acc[4]  = {};
      f32x4 accL[4] = {};
#pragma unroll
      for (int kt = 0; kt < 16; ++kt) {
        f16x8 a0 = *(const f16x8*)(aqh + kt * 32);
        f16x8 a1 = *(const f16x8*)(aql + kt * 32);
#pragma unroll
        for (int t4 = 0; t4 < 4; ++t4) {   // t4 = nh*2 + jt
          f16x8 bw = wh_[(t4 * 16 + kt) * 64 + ln];
          acc[t4]  = __builtin_amdgcn_mfma_f32_16x16x32_f16(a0, bw, acc[t4], 0, 0, 0);
          accL[t4] = __builtin_amdgcn_mfma_f32_16x16x32_f16(a1, bw, accL[t4], 0, 0, 0);
        }
      }
      // phase 2: p_s @ Wx1 (cross-XCD, slack-protected safe poll)
      pollS(pfSc, 16, (unsigned)(s + 1), ln);
      const f16* aph = (const f16*)p_hi + (size_t)slot_w * SLOT + (size_t)(rb + cl) * NH + qd * 8;
      const f16* apl = (const f16*)p_lo + (size_t)slot_w * SLOT + (size_t)(rb + cl) * NH + qd * 8;
#pragma unroll
      for (int kt = 0; kt < 16; ++kt) {
        f16x8 a0 = *(const f16x8*)(aph + kt * 32);
        f16x8 a1 = *(const f16x8*)(apl + kt * 32);
#pragma unroll
        for (int t4 = 0; t4 < 4; ++t4) {
          f16x8 bw = wx_[(t4 * 16 + kt) * 64 + ln];
          acc[t4]  = __builtin_amdgcn_mfma_f32_16x16x32_f16(a0, bw, acc[t4], 0, 0, 0);
          accL[t4] = __builtin_amdgcn_mfma_f32_16x16x32_f16(a1, bw, accL[t4], 0, 0, 0);
        }
      }
      f16* sh  = (f16*)(smem + 131072);    // 64 x 16 hi (2 KB)
      f16* slo = sh + 1024;                // 64 x 16 lo (2 KB)
      const bool hiH = (cl < 8);
#pragma unroll
      for (int e = 0; e < 4; ++e) {
        int r = wv * 16 + qd * 4 + e;
        int b = c * 64 + r;
        float po = 0.0f;
#pragma unroll
        for (int nh = 0; nh < 2; ++nh) {
          float v0 = acc[nh*2+0][e] + accL[nh*2+0][e] * LO + b1c0[nh];   // i / f
          float v1 = acc[nh*2+1][e] + accL[nh*2+1][e] * LO + b1c1[nh];   // g / o
          float w0 = __shfl_xor(v0, 8, 16);
          float w1 = __shfl_xor(v1, 8, 16);
          float gi = hiH ? v0 : w0;
          float gf = hiH ? w0 : v0;
          float gg = hiH ? v1 : w1;
          float go = hiH ? w1 : v1;
          float ii = sigm(gi), ff = sigm(gf), tg = tanhx(gg), oo = sigm(go);
          cst[nh][e] = ff * cst[nh][e] + ii * tg;
          float h = oo * tanhx(cst[nh][e]);
          int su = r * 16 + nh * 8 + (cl & 7);
          if (hiH) {
            sh[su] = (f16)h;
          } else {
            f16 hh = (f16)h;
            slo[su] = (f16)((h - (float)hh) * 1024.0f);
          }
          po += hiH ? wfv[nh] * h : 0.0f;
        }
#pragma unroll
        for (int m = 1; m < 16; m <<= 1) po += __shfl_xor(po, m, 16);
        if (cl == 0)
          atomicAdd(part8 + (size_t)(sl & 7) * (NB * NT_) + (size_t)b * NT_ + s, po);
      }
      __syncthreads();
      // coop WT store: 64 rows x 16 units x {hi,lo}, 8B pieces
      {
        unsigned short* bh = q_hi + (size_t)slot_w * SLOT;
        unsigned short* bl = q_lo + (size_t)slot_w * SLOT;
        for (int i = tid; i < 512; i += 256) {
          int strm = i >> 8, id2 = i & 255, r = id2 >> 2, j = id2 & 3;
          const f16* src = (strm ? slo : sh) + r * 16 + j * 4;
          unsigned short* dst = (strm ? bl : bh) + (size_t)(c * 64 + r) * NH + sl * 16 + j * 4;
          st8(dst, *(const u64*)src);
        }
      }
      __syncthreads();
      if (tid == 0) {
        *(volatile unsigned*)(qfFc + sl) = (unsigned)(s + 1);   // fast L2 flag
        __hip_atomic_store(qfSc + sl, (unsigned)(s + 1),
                           __ATOMIC_RELAXED, __HIP_MEMORY_SCOPE_AGENT);
      }
    }
  }
}

// ---------------------------------------------------------------------------
extern "C" void kernel_launch(void* const* d_in, const int* in_sizes, int n_in,
                              void* d_out, int out_size, void* d_ws, size_t ws_size,
                              hipStream_t stream) {
  (void)in_sizes; (void)n_in; (void)out_size; (void)ws_size;
  const float* inp = (const float*)d_in[0];
  const float* Wx0 = (const float*)d_in[1];
  const float* Wh0 = (const float*)d_in[2];
  const float* b0  = (const float*)d_in[3];
  const float* Wx1 = (const float*)d_in[4];
  const float* Wh1 = (const float*)d_in[5];
  const float* b1  = (const float*)d_in[6];
  const float* Wf  = (const float*)d_in[7];
  const float* bf  = (const float*)d_in[8];

  const size_t MB = 1u << 20;
  const size_t OFF_W    = 0;                 // 6 MiB tiled fp16 weights
  const size_t OFF_XT   = 6 * MB;            // 1 MiB
  const size_t OFF_PHI  = 7 * MB;            // 4 MiB (RING x 256 KB)
  const size_t OFF_PLO  = 11 * MB;
  const size_t OFF_QHI  = 15 * MB;
  const size_t OFF_QLO  = 19 * MB;
  const size_t OFF_PART = 23 * MB;           // 8 MiB
  const size_t OFF_CTR  = 31 * MB;           // sync: 3 KiB

  char* ws = (char*)d_ws;
  f16* wsl = (f16*)(ws + OFF_W);
  float* xT = (float*)(ws + OFF_XT);
  unsigned short* phi = (unsigned short*)(ws + OFF_PHI);
  unsigned short* plo = (unsigned short*)(ws + OFF_PLO);
  unsigned short* qhi = (unsigned short*)(ws + OFF_QHI);
  unsigned short* qlo = (unsigned short*)(ws + OFF_QLO);
  float* part8 = (float*)(ws + OFF_PART);
  unsigned int* syncp = (unsigned int*)(ws + OFF_CTR);
  float* out = (float*)d_out;

  hipFuncSetAttribute((const void*)lstm_main,
                      hipFuncAttributeMaxDynamicSharedMemorySize, 139264);

  // zero rings + partials + sync (contiguous)
  hipMemsetAsync(ws + OFF_PHI, 0, (OFF_CTR + 3072) - OFF_PHI, stream);

  prep_xT<<<1024, 256, 0, stream>>>(inp, xT);
  prep_w<<<12288, 256, 0, stream>>>(Wh0, Wx1, Wh1, wsl);

  lstm_main<<<256, 256, 139264, stream>>>(xT, wsl, Wx0, b0, b1, Wf,
                                          phi, plo, qhi, qlo, syncp, part8);

  reduce_out<<<1024, 256, 0, stream>>>(part8, bf, out);
}